// Round 13
// baseline (1009.958 us; speedup 1.0000x reference)
//
#include <hip/hip_runtime.h>
#include <hip/hip_fp16.h>
#include <math.h>

// ---------------------------------------------------------------------------
// RNN: h_{t+1} = relu(x_t @ W_in^T + h_t @ W_hh^T + b_hh + noise_t*scale)
// outputs: hidden_list [128,256,1024] f32, output_list [128,256,128] f32,
//          h_final [128,1024] f32 (concatenated flat in d_out)
//
// R13 = R9 (proven 762us: XCD-striped L2 exchange, tag-in-data, cooperative
// LDS staging) + FLAG-GATED spin:
//  - R5->R9 showed exchange medium (L3 vs L2) doesn't move the period; R6
//    showed cost is fixed per phase. Suspect: spin CONGESTION - each miss
//    round reloads 32KB/block; 16 blocks/XCD hammer L2 ~0.5-1KB/cy, delaying
//    producer store visibility and inflating every round. Detection quantum
//    = a full 32KB round.
//  - Fix: per-WAVE flags. Producer wave: publish stores -> vmcnt(0) ->
//    lane0 sets FLG[t+1][m][n*4+wave] (agent store; monotonic per-step
//    array, never reused -> no stale-line reuse hazard). Consumer wave:
//    lane i polls FLG[t][m][i] (4B/lane/round, 32x less traffic), sc0 fast
//    path + agent-load escalation, __all ballot. Data load happens ONCE
//    after the gate; tag validation (gen (t>>1)&1, sign bits) kept as the
//    authoritative backstop with sys-escalation -> liveness under ANY
//    blockIdx->XCD mapping even if flags mislead (they can't corrupt, only
//    gate early/late).
//  - Compute path byte-identical to R9: W chunks 0..29 LDS XOR-swizzled +
//    30,31 & x-chunks in regs, cooperative htile staging, 2 barriers,
//    36 MFMA/wave.
// ---------------------------------------------------------------------------

typedef _Float16 half8 __attribute__((ext_vector_type(8)));
typedef float    f32x4 __attribute__((ext_vector_type(4)));
typedef unsigned int u32x4 __attribute__((ext_vector_type(4)));
typedef unsigned long long u64;

#define SIGMA_F 0.05f

constexpr int T_  = 256;
constexpr int B_  = 128;
constexpr int NH  = 1024;
constexpr int NIN = 128;
constexpr int MB  = 16;           // batch rows per group

// workspace layout (bytes)
constexpr size_t OFF_XT  = 0;                            // fp16 [T][B][NIN] 8.39MB
constexpr size_t OFF_NB  = (size_t)T_*B_*NIN*2;          // f32  [T][NH]     1.05MB
constexpr size_t OFF_WO  = OFF_NB + (size_t)T_*NH*4;     // fp16 [NIN][NH]   0.26MB
constexpr size_t OFF_HB  = OFF_WO + (size_t)NIN*NH*2;    // u32 [2][B][512]  0.52MB
constexpr size_t OFF_FLG = OFF_HB + (size_t)2*B_*(NH/2)*4; // u32 [T][8][64] 0.52MB

__device__ __forceinline__ unsigned short f16bits(float v) {
    return __half_as_ushort(__float2half(v));
}
__device__ __forceinline__ u64 ald(const u64* p) {
    return __hip_atomic_load(p, __ATOMIC_RELAXED, __HIP_MEMORY_SCOPE_AGENT);
}
__device__ __forceinline__ unsigned int ald32(const unsigned int* p) {
    return __hip_atomic_load(p, __ATOMIC_RELAXED, __HIP_MEMORY_SCOPE_AGENT);
}
__device__ __forceinline__ void ast(unsigned int* p, unsigned int v) {
    __hip_atomic_store(p, v, __ATOMIC_RELAXED, __HIP_MEMORY_SCOPE_AGENT);
}

// 8x dwordx4 at 256B stride, sc0 (L1-bypass; L2-served when same-XCD).
__device__ __forceinline__ void ld8_sc0(u32x4 r[8], const u64* p) {
    asm volatile(
        "global_load_dwordx4 %0, %8, off sc0\n\t"
        "global_load_dwordx4 %1, %8, off offset:256 sc0\n\t"
        "global_load_dwordx4 %2, %8, off offset:512 sc0\n\t"
        "global_load_dwordx4 %3, %8, off offset:768 sc0\n\t"
        "global_load_dwordx4 %4, %8, off offset:1024 sc0\n\t"
        "global_load_dwordx4 %5, %8, off offset:1280 sc0\n\t"
        "global_load_dwordx4 %6, %8, off offset:1536 sc0\n\t"
        "global_load_dwordx4 %7, %8, off offset:1792 sc0\n\t"
        "s_waitcnt vmcnt(0)"
        : "=&v"(r[0]), "=&v"(r[1]), "=&v"(r[2]), "=&v"(r[3]),
          "=&v"(r[4]), "=&v"(r[5]), "=&v"(r[6]), "=&v"(r[7])
        : "v"(p)
        : "memory");
}

__device__ __forceinline__ unsigned int ld_flag_sc0(const unsigned int* p) {
    unsigned int v;
    asm volatile(
        "global_load_dword %0, %1, off sc0\n\t"
        "s_waitcnt vmcnt(0)"
        : "=v"(v) : "v"(p) : "memory");
    return v;
}

// ---------------------------------------------------------------------------
__global__ void setup_kernel(const float* __restrict__ X,
                             const float* __restrict__ hidden,
                             const float* __restrict__ b_hh,
                             const float* __restrict__ W_out,
                             const float* __restrict__ alpha_w,
                             const float* __restrict__ noise,
                             unsigned short* __restrict__ Xt,
                             float* __restrict__ NB,
                             unsigned short* __restrict__ Wo,
                             unsigned int* __restrict__ Hb0,
                             unsigned int* __restrict__ Hb1,
                             unsigned int* __restrict__ FLG)
{
    int idx = blockIdx.x * 256 + threadIdx.x;
    // X [B][T][NIN] -> Xt [T][B][NIN] fp16
    if (idx < B_ * T_ * NIN) {
        int d = idx & 127, rest = idx >> 7;
        int brow = rest & 127, t = rest >> 7;
        Xt[idx] = f16bits(X[((size_t)brow * T_ + t) * NIN + d]);
    }
    if (idx < T_ * NH) {
        int c = idx & (NH - 1);
        NB[idx] = b_hh[c] + noise[idx] * (sqrtf(2.0f / alpha_w[c]) * SIGMA_F);
    }
    if (idx < NIN * NH) Wo[idx] = f16bits(W_out[idx]);
    if (idx < B_ * NH / 2) {
        // slot0 = initial h with gen-0 tag (0); slot1 = poison (tag 1)
        unsigned int lo = f16bits(hidden[idx * 2]);
        unsigned int hi = f16bits(hidden[idx * 2 + 1]);
        Hb0[idx] = (lo | (hi << 16)) & 0x7FFF7FFFu;
        Hb1[idx] = 0x80008000u;
    }
    // flags: FLG[t][m][i]; t=0 pre-set (h_0 ready), rest zero
    if (idx < T_ * 8 * 64) FLG[idx] = (idx < 8 * 64) ? 1u : 0u;
}

// ---------------------------------------------------------------------------
// Persistent RNN: 128 blocks x 256 threads (4 waves, 1 block/CU).
// Roles: m = bx&7 (batch group, XCD-striped), n = bx>>3 (column slice).
__global__ __launch_bounds__(256, 1) void rnn_step_kernel(
    const float* __restrict__ W_hh, const float* __restrict__ W_in,
    const unsigned short* __restrict__ Xt, const float* __restrict__ NB,
    unsigned int* __restrict__ Hb0, unsigned int* __restrict__ Hb1,
    unsigned int* __restrict__ FLG,
    float* __restrict__ hidden_list, float* __restrict__ h_final)
{
    __shared__ unsigned short wtile[64 * 960];    // 122,880 B (chunks 0..29)
    __shared__ unsigned short htile[16 * 1024];   //  32,768 B (group h tile)

    const int tid = threadIdx.x;
    const int m = blockIdx.x & 7;    // batch group (XCD-striped)
    const int n = blockIdx.x >> 3;   // column slice

    // ---- stage W chunks 0..29 into LDS (XOR-swizzled 16B granules) ----
    for (int g = tid; g < 64 * 120; g += 256) {
        int row = g / 120, G = g - row * 120;
        const float* s = W_hh + (size_t)(n * 64 + row) * NH + G * 8;
        half8 h;
        #pragma unroll
        for (int j = 0; j < 8; ++j) h[j] = (_Float16)s[j];
        *(half8*)&wtile[row * 960 + ((G ^ (row & 7)) << 3)] = h;
    }

    const int wave = tid >> 6, lane = tid & 63;
    const int l15 = lane & 15, lk = lane >> 4;
    const int colW = wave * 16 + l15;       // local W row / output col
    const int gcol = n * 64 + colW;         // global hidden col

    // ---- per-lane register B-fragments: W_hh chunks 30,31 + W_in 4 chunks ----
    auto cvt8 = [](const float* s) {
        half8 h;
        #pragma unroll
        for (int j = 0; j < 8; ++j) h[j] = (_Float16)s[j];
        return h;
    };
    half8 bh30 = cvt8(W_hh + (size_t)gcol * NH + 960 + lk * 8);
    half8 bh31 = cvt8(W_hh + (size_t)gcol * NH + 992 + lk * 8);
    half8 bx[4];
    #pragma unroll
    for (int kx = 0; kx < 4; ++kx)
        bx[kx] = cvt8(W_in + (size_t)gcol * NIN + kx * 32 + lk * 8);
    __syncthreads();

    // h staging role: thread (hrow, part); 8 granules G=j*16+part of row hrow
    const int hrow = tid >> 4;       // 0..15
    const int part = tid & 15;

    const int rowA = m * MB + l15;

    auto xpart = [&](int t) -> f32x4 {
        f32x4 a = {0.f, 0.f, 0.f, 0.f};
        const half8* xp = (const half8*)(Xt + ((size_t)t * B_ + rowA) * NIN) + lk;
        #pragma unroll
        for (int kx = 0; kx < 4; ++kx)
            a = __builtin_amdgcn_mfma_f32_16x16x32_f16(xp[kx * 4], bx[kx], a, 0, 0, 0);
        return a;
    };

    f32x4 accx = xpart(0);

    for (int t = 0; t < T_; ++t) {
        // ---- phase 0: flag gate (per wave; lane i polls flag i) ----
        {
            const unsigned int* fp = FLG + ((size_t)t * 8 + m) * 64 + lane;
            int fr = 0;
            for (;;) {
                unsigned int fv = (fr < 6) ? ld_flag_sc0(fp) : ald32(fp);
                if (__all(fv != 0u)) break;
                ++fr;
                if (fr >= 2) __builtin_amdgcn_s_sleep(2);
            }
        }

        const u64* hp = (const u64*)((t & 1) ? Hb1 : Hb0)
                        + (size_t)(m * MB + hrow) * 256 + part * 2;
        const unsigned int e32 = ((t >> 1) & 1) ? 0x80008000u : 0u;

        // ---- phase 1: single cooperative tagged load (backstop validate) ----
        u32x4 r[8];
        {
            int round = 0;
            for (;;) {
                if (round < 6) {
                    ld8_sc0(r, hp);
                } else {
                    #pragma unroll
                    for (int j = 0; j < 8; ++j) {
                        u64 a = ald(hp + (size_t)j * 32);
                        u64 b = ald(hp + (size_t)j * 32 + 1);
                        r[j][0] = (unsigned int)a; r[j][1] = (unsigned int)(a >> 32);
                        r[j][2] = (unsigned int)b; r[j][3] = (unsigned int)(b >> 32);
                    }
                }
                unsigned int red = 0;
                #pragma unroll
                for (int j = 0; j < 8; ++j) {
                    #pragma unroll
                    for (int k = 0; k < 4; ++k) red |= r[j][k] ^ e32;
                }
                if (!(red & 0x80008000u)) break;
                ++round;
                if (round >= 3) __builtin_amdgcn_s_sleep(1);
            }
        }

        __syncthreads();   // B1: all htile(t-1) reads complete (WAR)

        // strip tags, stage to LDS (swizzled granules)
        #pragma unroll
        for (int j = 0; j < 8; ++j) {
            u32x4 w;
            #pragma unroll
            for (int k = 0; k < 4; ++k) w[k] = r[j][k] & 0x7FFF7FFFu;
            int G = j * 16 + part;
            *(half8*)&htile[hrow * 1024 + ((G ^ (hrow & 7)) << 3)] =
                __builtin_bit_cast(half8, w);
        }

        __syncthreads();   // B2: htile ready

        // ---- phase 2: 36 MFMAs (30 LDS-B + 2 reg-B; 4 x-chunks in accx) ----
        f32x4 acc = accx;
        #pragma unroll
        for (int ki = 0; ki < 30; ++ki) {
            int G = 4 * ki + lk;
            half8 av = *(const half8*)&htile[l15 * 1024 + ((G ^ (l15 & 7)) << 3)];
            half8 bv = *(const half8*)&wtile[colW * 960 + ((G ^ (colW & 7)) << 3)];
            acc = __builtin_amdgcn_mfma_f32_16x16x32_f16(av, bv, acc, 0, 0, 0);
        }
        {
            int G = 120 + lk;
            half8 av = *(const half8*)&htile[l15 * 1024 + ((G ^ (l15 & 7)) << 3)];
            acc = __builtin_amdgcn_mfma_f32_16x16x32_f16(av, bh30, acc, 0, 0, 0);
            G = 124 + lk;
            av = *(const half8*)&htile[l15 * 1024 + ((G ^ (l15 & 7)) << 3)];
            acc = __builtin_amdgcn_mfma_f32_16x16x32_f16(av, bh31, acc, 0, 0, 0);
        }

        // ---- bias+noise, relu ----
        const float nb = NB[t * NH + gcol];
        float hv[4];
        #pragma unroll
        for (int r2 = 0; r2 < 4; ++r2) {
            float v = acc[r2] + nb;
            hv[r2] = v > 0.f ? v : 0.f;
        }

        // ---- publish h_{t+1}, drain, set flag (per wave) ----
        if (t < T_ - 1) {
            unsigned int* hn = (t & 1) ? Hb0 : Hb1;
            const unsigned int tagb = (((t + 1) >> 1) & 1) ? 0x80008000u : 0u;
            #pragma unroll
            for (int r2 = 0; r2 < 4; ++r2) {
                float other = __shfl_xor(hv[r2], 1);
                if (!(lane & 1)) {
                    unsigned int val = (unsigned int)f16bits(hv[r2]) |
                                       ((unsigned int)f16bits(other) << 16) | tagb;
                    int brow = m * MB + lk * 4 + r2;
                    ast(&hn[(size_t)brow * 512 + (gcol >> 1)], val);
                }
            }
            asm volatile("s_waitcnt vmcnt(0)" ::: "memory"); // wave's stores done
            if (lane == 0)
                ast(FLG + ((size_t)(t + 1) * 8 + m) * 64 + n * 4 + wave, 1u);
        }

        // ---- off-critical-path: fp32 outputs, next x-part ----
        #pragma unroll
        for (int r2 = 0; r2 < 4; ++r2) {
            int brow = m * MB + lk * 4 + r2;
            hidden_list[((size_t)brow * T_ + t) * NH + gcol] = hv[r2];
        }
        if (t == T_ - 1) {
            #pragma unroll
            for (int r2 = 0; r2 < 4; ++r2) {
                int brow = m * MB + lk * 4 + r2;
                h_final[(size_t)brow * NH + gcol] = hv[r2];
            }
        } else {
            accx = xpart(t + 1);
        }
    }
}

// ---------------------------------------------------------------------------
// Readout: Y[32768,128] = HL[32768,1024](f32->f16) @ Wo^T(f16), fp32 out.
__global__ __launch_bounds__(256, 4) void ygemm_kernel(
    const float* __restrict__ HL, const unsigned short* __restrict__ Wo,
    float* __restrict__ Y)
{
    typedef unsigned short ushort8 __attribute__((ext_vector_type(8)));
    const int tid = threadIdx.x;
    const int wave = tid >> 6, lane = tid & 63;
    const int l15 = lane & 15, lk = lane >> 4;
    const size_t rowbase = (size_t)blockIdx.x * 64;

    f32x4 acc[4][2] = {};

    #pragma unroll 2
    for (int ki = 0; ki < 32; ++ki) {
        const int k0 = ki * 32 + lk * 8;
        half8 bfr[2];
        #pragma unroll
        for (int nt = 0; nt < 2; ++nt) {
            int ncol = (wave * 2 + nt) * 16 + l15;
            ushort8 braw = *(const ushort8*)(Wo + ncol * NH + k0);
            bfr[nt] = __builtin_bit_cast(half8, braw);
        }
        #pragma unroll
        for (int mt = 0; mt < 4; ++mt) {
            size_t row = rowbase + mt * 16 + l15;
            const float4* ap = (const float4*)(HL + row * NH + k0);
            float4 a0 = ap[0];
            float4 a1 = ap[1];
            half8 a = { (_Float16)a0.x, (_Float16)a0.y, (_Float16)a0.z, (_Float16)a0.w,
                        (_Float16)a1.x, (_Float16)a1.y, (_Float16)a1.z, (_Float16)a1.w };
            #pragma unroll
            for (int nt = 0; nt < 2; ++nt)
                acc[mt][nt] = __builtin_amdgcn_mfma_f32_16x16x32_f16(a, bfr[nt], acc[mt][nt], 0, 0, 0);
        }
    }

    #pragma unroll
    for (int mt = 0; mt < 4; ++mt) {
        #pragma unroll
        for (int nt = 0; nt < 2; ++nt) {
            int ncol = (wave * 2 + nt) * 16 + l15;
            #pragma unroll
            for (int r = 0; r < 4; ++r) {
                size_t row = rowbase + mt * 16 + lk * 4 + r;
                Y[row * NIN + ncol] = acc[mt][nt][r];
            }
        }
    }
}

// ---------------------------------------------------------------------------
extern "C" void kernel_launch(void* const* d_in, const int* in_sizes, int n_in,
                              void* d_out, int out_size, void* d_ws, size_t ws_size,
                              hipStream_t stream)
{
    const float* X      = (const float*)d_in[0];
    const float* hidden = (const float*)d_in[1];
    const float* W_in   = (const float*)d_in[2];
    const float* W_hh   = (const float*)d_in[3];
    const float* b_hh   = (const float*)d_in[4];
    const float* W_out  = (const float*)d_in[5];
    const float* alpha  = (const float*)d_in[6];
    const float* noise  = (const float*)d_in[7];

    char* ws = (char*)d_ws;   // ~10.7 MB
    unsigned short* Xt = (unsigned short*)(ws + OFF_XT);
    float*          NB = (float*)(ws + OFF_NB);
    unsigned short* Wo = (unsigned short*)(ws + OFF_WO);
    unsigned int*  Hb0 = (unsigned int*)(ws + OFF_HB);
    unsigned int*  Hb1 = Hb0 + (size_t)B_ * NH / 2;
    unsigned int*  FLG = (unsigned int*)(ws + OFF_FLG);

    float* hidden_list = (float*)d_out;                                  // [128,256,1024]
    float* output_list = hidden_list + (size_t)B_ * T_ * NH;             // [128,256,128]
    float* h_final     = output_list + (size_t)B_ * T_ * NIN;            // [128,1024]

    setup_kernel<<<(B_ * T_ * NIN + 255) / 256, 256, 0, stream>>>(
        X, hidden, b_hh, W_out, alpha, noise, Xt, NB, Wo, Hb0, Hb1, FLG);

    rnn_step_kernel<<<128, 256, 0, stream>>>(
        W_hh, W_in, Xt, NB, Hb0, Hb1, FLG, hidden_list, h_final);

    ygemm_kernel<<<(B_ * T_) / 64, 256, 0, stream>>>(
        hidden_list, Wo, output_list);
}